// Round 1
// baseline (1061.172 us; speedup 1.0000x reference)
//
#include <hip/hip_runtime.h>
#include <math.h>

#define RR 512
#define RR2 (RR*RR)
#define PP 256
#define PP2 (PP*PP)

__device__ inline float2 cxmul(float2 a, float2 b) {
  return make_float2(a.x*b.x - a.y*b.y, a.x*b.y + a.y*b.x);
}

// ---------------- height map: hm = sum_t zc[t]*zv[t] ----------------
__global__ void k_height(const float* __restrict__ zc, const float* __restrict__ zv,
                         float* __restrict__ hm) {
  int idx = blockIdx.x * 256 + threadIdx.x;
  float s = 0.f;
  #pragma unroll 8
  for (int t = 0; t < 64; ++t) s += zc[t] * zv[(size_t)t * RR2 + idx];
  hm[idx] = s;
}

// ---------------- aux 8x8x3 color mask tile ----------------
__global__ void k_aux(const float* __restrict__ mp, const float* __restrict__ cf,
                      float* __restrict__ aux8) {
  int idx = threadIdx.x;           // 192 threads: i*24 + j*3 + l
  if (idx >= 192) return;
  int l = idx % 3, j = (idx / 3) & 7, i = idx / 24;
  int i4 = (i < 4) ? i : 7 - i;
  int j4 = (j < 4) ? j : 7 - j;
  float s = 0.f;
  for (int f = 0; f < 4; ++f) s += cf[f*3 + l] * mp[f*16 + i4*4 + j4];
  aux8[idx] = s;
}

// ---------------- pupil field: exp(i*K*hm) * aperture ----------------
__global__ void k_field(const float* __restrict__ hm, float2* __restrict__ A, float K) {
  int idx = blockIdx.x * 256 + threadIdx.x;
  int i = idx >> 9, j = idx & 511;
  int dx = i - 256, dy = j - 256;
  float2 v = make_float2(0.f, 0.f);
  if (dx*dx + dy*dy < 65025) {          // radius < 255 (xg.max())
    float ph = K * hm[idx];
    float s, c;
    sincosf(ph, &s, &c);
    v = make_float2(c, s);
  }
  A[idx] = v;
}

// ---------------- angular-spectrum transfer function ----------------
__global__ void k_transfer(float2* __restrict__ Hb, double wl, double dist) {
  int idx = blockIdx.x * 256 + threadIdx.x;
  int u = idx >> 9, v = idx & 511;
  double inv_nd = 1.0 / (512.0 * 3.69e-6);
  double fu = (double)((u < 256) ? u : u - 512) * inv_nd;
  double fv = (double)((v < 256) ? v : v - 512) * inv_nd;
  double au = wl * fu, av = wl * fv;
  double argd = 1.0 - au*au - av*av;
  float2 h = make_float2(0.f, 0.f);
  if (argd > 0.0) {
    double kz = (6.283185307179586 / wl) * sqrt(argd);
    double ph = fmod(dist * kz, 6.283185307179586);
    float s, c;
    __sincosf((float)ph, &s, &c);
    h = make_float2(c, s);
  }
  Hb[idx] = h;
}

// ---------------- pointwise complex multiply by H (broadcast over planes) ----
__global__ void k_mulH(float2* __restrict__ d, const float2* __restrict__ Hb, int mask) {
  int idx = blockIdx.x * 256 + threadIdx.x;
  d[idx] = cxmul(d[idx], Hb[idx & mask]);
}

// ---------------- expand u1 by 16 shifted masks ----------------
__global__ void k_expand(const float2* __restrict__ u1, const float* __restrict__ aux8,
                         float2* __restrict__ U, int band, int k0) {
  int idx = blockIdx.x * 256 + threadIdx.x;     // 8 * RR2
  int k = (idx >> 18) + k0;
  int rc = idx & (RR2 - 1);
  int r = rc >> 9, c = rc & 511;
  int ri = k >> 2, rj = k & 3;
  // mov = {0,0,-1,-1} => mi = -(ri>>1); (r - mi) & 7 = (r + (ri>>1)) & 7
  int i8 = (r + (ri >> 1)) & 7;
  int j8 = (c + (rj >> 1)) & 7;
  float m = aux8[(i8*8 + j8)*3 + band];
  float2 v = u1[rc];
  U[idx] = make_float2(v.x*m, v.y*m);
}

// ---------------- |u3|^2, 2x2 mean downsample ----------------
__global__ void k_psf(const float2* __restrict__ U, float* __restrict__ PSF) {
  int idx = blockIdx.x * 256 + threadIdx.x;     // 8 * PP2
  int k = idx >> 16, ij = idx & 65535;
  int i = ij >> 8, j = ij & 255;
  const float2* p = U + ((size_t)k << 18);
  float s = 0.f;
  #pragma unroll
  for (int a = 0; a < 2; ++a)
    #pragma unroll
    for (int b2 = 0; b2 < 2; ++b2) {
      float2 v = p[((2*i + a) << 9) | (2*j + b2)];
      s += v.x*v.x + v.y*v.y;
    }
  PSF[idx] = 0.25f * s;
}

// ---------------- per-psf sum (one block per psf) ----------------
__global__ void k_psfsum(const float* __restrict__ PSF, float* __restrict__ PSUM) {
  __shared__ float red[256];
  int k = blockIdx.x, t = threadIdx.x;
  float s = 0.f;
  for (int i = t; i < PP2; i += 256) s += PSF[(k << 16) + i];
  red[t] = s;
  __syncthreads();
  for (int o = 128; o > 0; o >>= 1) {
    if (t < o) red[t] += red[t + o];
    __syncthreads();
  }
  if (t == 0) PSUM[k] = red[0];
}

// ---------------- normalized + ifftshifted psf -> complex OTF input ----------
__global__ void k_otf(const float* __restrict__ PSF, const float* __restrict__ PSUM,
                      float2* __restrict__ OTF) {
  int idx = blockIdx.x * 256 + threadIdx.x;     // 16 * PP2
  int k = idx >> 16, ij = idx & 65535;
  int i = ij >> 8, j = ij & 255;
  int si = (i + 128) & 255, sj = (j + 128) & 255;
  float v = PSF[(k << 16) | (si << 8) | sj] / PSUM[k];
  OTF[idx] = make_float2(v, 0.f);
}

// ---------------- combine OTFs with comb-phases: W_ab = (1/16) sum_k w^(a*ri+b*rj) OTF_k
__global__ void k_wbuild(const float2* __restrict__ OTF, float2* __restrict__ Wb) {
  int uv = blockIdx.x * 256 + threadIdx.x;      // PP2
  float2 o[16];
  #pragma unroll
  for (int k = 0; k < 16; ++k) o[k] = OTF[(k << 16) | uv];
  #pragma unroll
  for (int a = 0; a < 4; ++a) {
    #pragma unroll
    for (int b2 = 0; b2 < 4; ++b2) {
      float2 acc = make_float2(0.f, 0.f);
      #pragma unroll
      for (int k = 0; k < 16; ++k) {
        int t = (a*(k >> 2) + b2*(k & 3)) & 3;   // omega = -i
        float2 z = o[k];
        float2 r = (t == 0) ? z
                 : (t == 1) ? make_float2(z.y, -z.x)
                 : (t == 2) ? make_float2(-z.x, -z.y)
                 :            make_float2(-z.y, z.x);
        acc.x += r.x; acc.y += r.y;
      }
      Wb[((a*4 + b2) << 16) | uv] = make_float2(acc.x * (1.f/16.f), acc.y * (1.f/16.f));
    }
  }
}

// ---------------- load one band of inputs into complex buffer ----------------
__global__ void k_xload(const float* __restrict__ in, float2* __restrict__ X, int band) {
  int idx = blockIdx.x * 256 + threadIdx.x;     // NB * PP2
  X[idx] = make_float2(in[(size_t)idx * 3 + band], 0.f);
}

// ---------------- Y_n = sum_ab W_ab .* shift(X_n) ----------------
__global__ void k_ybuild(const float2* __restrict__ X, const float2* __restrict__ Wb,
                         float2* __restrict__ Y) {
  int idx = blockIdx.x * 256 + threadIdx.x;     // NB * PP2
  int n = idx >> 16, uv = idx & 65535;
  int u = uv >> 8, v = uv & 255;
  const float2* Xn = X + ((size_t)n << 16);
  float2 acc = make_float2(0.f, 0.f);
  #pragma unroll
  for (int a = 0; a < 4; ++a) {
    int iu = (u - 64*a) & 255;
    #pragma unroll
    for (int b2 = 0; b2 < 4; ++b2) {
      int iv = (v - 64*b2) & 255;
      float2 w = Wb[((a*4 + b2) << 16) | uv];
      float2 x = Xn[(iu << 8) | iv];
      acc.x += w.x*x.x - w.y*x.y;
      acc.y += w.x*x.y + w.y*x.x;
    }
  }
  Y[idx] = acc;
}

// ---------------- accumulate 3 output channels ----------------
__global__ void k_accum(const float2* __restrict__ Y, float* __restrict__ out,
                        const float* __restrict__ cf, int band) {
  int idx = blockIdx.x * 256 + threadIdx.x;     // NB * PP2
  float re = Y[idx].x;
  float c0 = cf[band], c1 = cf[3 + band], c2 = cf[9 + band];
  float* o = out + (size_t)idx * 3;
  o[0] += c0 * re;
  o[1] += c1 * re;
  o[2] += c2 * re;
}

// ================= FFT kernels (Stockham radix-2 in LDS) =================
// Forward: X[u] = sum_i x_i e^{-2pi i u i/N}   (numpy convention)
// Inverse: conjugated twiddles, x1/N per 1D pass.

template<int N, bool INV>
__global__ __launch_bounds__(N/2) void k_fft_rows(float2* __restrict__ data) {
  constexpr int LOGN = (N == 512) ? 9 : 8;
  __shared__ float2 buf[2][N];
  const int t = threadIdx.x;
  float2* row = data + (size_t)blockIdx.x * N;
  buf[0][t] = row[t];
  buf[0][t + N/2] = row[t + N/2];
  int m = 1, cur = 0;
  #pragma unroll
  for (int s = 0; s < LOGN; ++s) {
    __syncthreads();
    int jm = t & ~(m - 1);
    float2 a = buf[cur][t];
    float2 b = buf[cur][t + N/2];
    float ang = (INV ? 6.2831853071795864769f : -6.2831853071795864769f)
                * (float)jm * (1.0f / (float)N);
    float sn, cs;
    __sincosf(ang, &sn, &cs);
    float2 d = make_float2(a.x - b.x, a.y - b.y);
    buf[cur ^ 1][t + jm]     = make_float2(a.x + b.x, a.y + b.y);
    buf[cur ^ 1][t + jm + m] = make_float2(d.x*cs - d.y*sn, d.x*sn + d.y*cs);
    cur ^= 1; m <<= 1;
  }
  __syncthreads();
  if (INV) {
    constexpr float sc = 1.0f / (float)N;
    float2 v0 = buf[cur][t], v1 = buf[cur][t + N/2];
    row[t]       = make_float2(v0.x*sc, v0.y*sc);
    row[t + N/2] = make_float2(v1.x*sc, v1.y*sc);
  } else {
    row[t]       = buf[cur][t];
    row[t + N/2] = buf[cur][t + N/2];
  }
}

template<int N, int CB, int W, bool INV>
__global__ __launch_bounds__(CB*W) void k_fft_cols(float2* __restrict__ data) {
  constexpr int LOGN = (N == 512) ? 9 : 8;
  __shared__ float2 buf[2][N][CB];
  const int c = threadIdx.x;   // column within tile
  const int w = threadIdx.y;   // worker
  float2* img = data + (size_t)blockIdx.y * N * N + (size_t)blockIdx.x * CB + c;
  for (int r = w; r < N; r += W) buf[0][r][c] = img[(size_t)r * N];
  int m = 1, cur = 0;
  #pragma unroll
  for (int s = 0; s < LOGN; ++s) {
    __syncthreads();
    for (int t = w; t < N/2; t += W) {
      int jm = t & ~(m - 1);
      float2 a = buf[cur][t][c];
      float2 b = buf[cur][t + N/2][c];
      float ang = (INV ? 6.2831853071795864769f : -6.2831853071795864769f)
                  * (float)jm * (1.0f / (float)N);
      float sn, cs;
      __sincosf(ang, &sn, &cs);
      float2 d = make_float2(a.x - b.x, a.y - b.y);
      buf[cur ^ 1][t + jm][c]     = make_float2(a.x + b.x, a.y + b.y);
      buf[cur ^ 1][t + jm + m][c] = make_float2(d.x*cs - d.y*sn, d.x*sn + d.y*cs);
    }
    cur ^= 1; m <<= 1;
  }
  __syncthreads();
  if (INV) {
    constexpr float sc = 1.0f / (float)N;
    for (int r = w; r < N; r += W) {
      float2 v = buf[cur][r][c];
      img[(size_t)r * N] = make_float2(v.x*sc, v.y*sc);
    }
  } else {
    for (int r = w; r < N; r += W) img[(size_t)r * N] = buf[cur][r][c];
  }
}

// ================= host-side dispatch =================

static inline void FFT512(float2* d, int nb, bool inv, hipStream_t s) {
  if (!inv) {
    k_fft_rows<512, false><<<512 * nb, 256, 0, s>>>(d);
    k_fft_cols<512, 4, 64, false><<<dim3(128, nb), dim3(4, 64), 0, s>>>(d);
  } else {
    k_fft_rows<512, true><<<512 * nb, 256, 0, s>>>(d);
    k_fft_cols<512, 4, 64, true><<<dim3(128, nb), dim3(4, 64), 0, s>>>(d);
  }
}

static inline void FFT256(float2* d, int nb, bool inv, hipStream_t s) {
  if (!inv) {
    k_fft_rows<256, false><<<256 * nb, 128, 0, s>>>(d);
    k_fft_cols<256, 8, 32, false><<<dim3(32, nb), dim3(8, 32), 0, s>>>(d);
  } else {
    k_fft_rows<256, true><<<256 * nb, 128, 0, s>>>(d);
    k_fft_cols<256, 8, 32, true><<<dim3(32, nb), dim3(8, 32), 0, s>>>(d);
  }
}

extern "C" void kernel_launch(void* const* d_in, const int* in_sizes, int n_in,
                              void* d_out, int out_size, void* d_ws, size_t ws_size,
                              hipStream_t stream) {
  const float* inp = (const float*)d_in[0];   // (8,256,256,3)
  const float* zc  = (const float*)d_in[1];   // (64,1,1)
  const float* zv  = (const float*)d_in[2];   // (64,512,512)
  const float* mp  = (const float*)d_in[3];   // (4,4,4)
  const float* cf  = (const float*)d_in[4];   // (4,3)
  float* out = (float*)d_out;                 // (8,256,256,3)

  char* ws = (char*)d_ws;
  size_t off = 0;
  auto alloc = [&](size_t bytes) -> void* {
    void* p = ws + off;
    off = (off + bytes + 255) & ~(size_t)255;
    return p;
  };
  float*  hm   = (float*) alloc((size_t)RR2 * 4);        // 1 MB
  float*  aux8 = (float*) alloc(192 * 4);
  float2* A    = (float2*)alloc((size_t)RR2 * 8);        // 2 MB  (field / u1)
  float2* HB   = (float2*)alloc((size_t)RR2 * 8);        // 2 MB
  float*  PSF  = (float*) alloc((size_t)16 * PP2 * 4);   // 4 MB
  float*  PSUM = (float*) alloc(16 * 4);
  float2* OTF  = (float2*)alloc((size_t)16 * PP2 * 8);   // 8 MB
  float2* Wb   = (float2*)alloc((size_t)16 * PP2 * 8);   // 8 MB
  float2* U    = (float2*)alloc((size_t)8 * RR2 * 8);    // 16 MB (psf chunk of 8)
  float2* X = U;                       // alias (U dead by conv stage): 4 MB
  float2* Y = U + (size_t)4 * RR2;     // alias at +8 MB: 4 MB

  hipMemsetAsync(d_out, 0, (size_t)out_size * sizeof(float), stream);

  k_height<<<RR2 / 256, 256, 0, stream>>>(zc, zv, hm);
  k_aux<<<1, 192, 0, stream>>>(mp, cf, aux8);

  const double wls[3] = {4.6e-7, 5.4e-7, 6.2e-7};
  const double dn[3]  = {0.52, 0.515, 0.51};
  const double DIST = 0.05, DIST_CODE = 0.047;

  for (int b = 0; b < 3; ++b) {
    float K = (float)(2.0 * M_PI / wls[b] * dn[b]);
    // field -> u1
    k_field<<<RR2 / 256, 256, 0, stream>>>(hm, A, K);
    FFT512(A, 1, false, stream);
    k_transfer<<<RR2 / 256, 256, 0, stream>>>(HB, wls[b], DIST_CODE);
    k_mulH<<<RR2 / 256, 256, 0, stream>>>(A, HB, RR2 - 1);
    FFT512(A, 1, true, stream);
    // u3 for 16 shifted masks (fused H(-dc)*H(d) = H(d-dc)), in 2 chunks of 8
    k_transfer<<<RR2 / 256, 256, 0, stream>>>(HB, wls[b], DIST - DIST_CODE);
    for (int ch = 0; ch < 2; ++ch) {
      k_expand<<<8 * RR2 / 256, 256, 0, stream>>>(A, aux8, U, b, ch * 8);
      FFT512(U, 8, false, stream);
      k_mulH<<<8 * RR2 / 256, 256, 0, stream>>>(U, HB, RR2 - 1);
      FFT512(U, 8, true, stream);
      k_psf<<<8 * PP2 / 256, 256, 0, stream>>>(U, PSF + (size_t)ch * 8 * PP2);
    }
    // normalize -> OTFs
    k_psfsum<<<16, 256, 0, stream>>>(PSF, PSUM);
    k_otf<<<16 * PP2 / 256, 256, 0, stream>>>(PSF, PSUM, OTF);
    FFT256(OTF, 16, false, stream);
    k_wbuild<<<PP2 / 256, 256, 0, stream>>>(OTF, Wb);
    // convolution via comb identity: 1 FFT + combine + 1 IFFT per image
    k_xload<<<8 * PP2 / 256, 256, 0, stream>>>(inp, X, b);
    FFT256(X, 8, false, stream);
    k_ybuild<<<8 * PP2 / 256, 256, 0, stream>>>(X, Wb, Y);
    FFT256(Y, 8, true, stream);
    k_accum<<<8 * PP2 / 256, 256, 0, stream>>>(Y, out, cf, b);
  }
}

// Round 2
// 418.076 us; speedup vs baseline: 2.5382x; 2.5382x over previous
//
#include <hip/hip_runtime.h>
#include <math.h>

#define RR 512
#define RR2 (RR*RR)
#define PP 256
#define PP2 (PP*PP)

// ---------------- height map: hm = sum_t zc[t]*zv[t] ----------------
__global__ void k_height(const float* __restrict__ zc, const float* __restrict__ zv,
                         float* __restrict__ hm) {
  int idx = blockIdx.x * 256 + threadIdx.x;
  float s = 0.f;
  #pragma unroll 8
  for (int t = 0; t < 64; ++t) s += zc[t] * zv[(size_t)t * RR2 + idx];
  hm[idx] = s;
}

// ---------------- aux 8x8x3 color mask tile ----------------
__global__ void k_aux(const float* __restrict__ mp, const float* __restrict__ cf,
                      float* __restrict__ aux8) {
  int idx = threadIdx.x;           // 192 threads: i*24 + j*3 + l
  if (idx >= 192) return;
  int l = idx % 3, j = (idx / 3) & 7, i = idx / 24;
  int i4 = (i < 4) ? i : 7 - i;
  int j4 = (j < 4) ? j : 7 - j;
  float s = 0.f;
  for (int f = 0; f < 4; ++f) s += cf[f*3 + l] * mp[f*16 + i4*4 + j4];
  aux8[idx] = s;
}

// ---------------- pupil field: exp(i*K*hm) * aperture ----------------
__global__ void k_field(const float* __restrict__ hm, float2* __restrict__ A, float K) {
  int idx = blockIdx.x * 256 + threadIdx.x;
  int i = idx >> 9, j = idx & 511;
  int dx = i - 256, dy = j - 256;
  float2 v = make_float2(0.f, 0.f);
  if (dx*dx + dy*dy < 65025) {          // radius < 255
    float ph = K * hm[idx];
    float s, c;
    sincosf(ph, &s, &c);
    v = make_float2(c, s);
  }
  A[idx] = v;
}

// ---------------- angular-spectrum transfer function ----------------
__global__ void k_transfer(float2* __restrict__ Hb, double wl, double dist) {
  int idx = blockIdx.x * 256 + threadIdx.x;
  int u = idx >> 9, v = idx & 511;
  double inv_nd = 1.0 / (512.0 * 3.69e-6);
  double fu = (double)((u < 256) ? u : u - 512) * inv_nd;
  double fv = (double)((v < 256) ? v : v - 512) * inv_nd;
  double au = wl * fu, av = wl * fv;
  double argd = 1.0 - au*au - av*av;
  float2 h = make_float2(0.f, 0.f);
  if (argd > 0.0) {
    double kz = (6.283185307179586 / wl) * sqrt(argd);
    double ph = fmod(dist * kz, 6.283185307179586);
    float s, c;
    __sincosf((float)ph, &s, &c);
    h = make_float2(c, s);
  }
  Hb[idx] = h;
}

// ================= FFT row kernels (Stockham radix-2 in LDS) =================
// Forward: X[u] = sum_i x_i e^{-2pi i u i/N}; inverse conj + 1/N per pass.

#define FFT_CORE(N, LOGN, INV)                                              \
  int m = 1, cur = 0;                                                       \
  _Pragma("unroll")                                                         \
  for (int s = 0; s < LOGN; ++s) {                                          \
    __syncthreads();                                                        \
    int jm = t & ~(m - 1);                                                  \
    float2 a = buf[cur][t];                                                 \
    float2 b = buf[cur][t + N/2];                                           \
    float ang = (INV ? 6.2831853071795864769f : -6.2831853071795864769f)    \
                * (float)jm * (1.0f / (float)N);                            \
    float sn, cs;                                                           \
    __sincosf(ang, &sn, &cs);                                               \
    float2 d = make_float2(a.x - b.x, a.y - b.y);                           \
    buf[cur ^ 1][t + jm]     = make_float2(a.x + b.x, a.y + b.y);           \
    buf[cur ^ 1][t + jm + m] = make_float2(d.x*cs - d.y*sn, d.x*sn + d.y*cs);\
    cur ^= 1; m <<= 1;                                                      \
  }                                                                         \
  __syncthreads();

// --- 512 rows forward, plain ---
__global__ __launch_bounds__(256) void k_r512_fwd(float2* __restrict__ data) {
  __shared__ float2 buf[2][512];
  const int t = threadIdx.x;
  float2* row = data + (size_t)blockIdx.x * 512;
  buf[0][t] = row[t];
  buf[0][t + 256] = row[t + 256];
  FFT_CORE(512, 9, false)
  row[t] = buf[cur][t];
  row[t + 256] = buf[cur][t + 256];
}

// --- 512 rows forward, fused mask expand: U[p] = u1 * shifted-mask(p) ---
__global__ __launch_bounds__(256) void k_r512_fwd_expand(
    const float2* __restrict__ u1, const float* __restrict__ aux8,
    float2* __restrict__ U, int band) {
  __shared__ float2 buf[2][512];
  const int t = threadIdx.x;
  int g = blockIdx.x;              // p*512 + r,  p in [0,4)
  int p = g >> 9, r = g & 511;
  int i8 = (r + (p >> 1)) & 7;
  const float* arow = aux8 + i8 * 24 + band;   // aux8[(i8*8+j8)*3+band]
  const float2* src = u1 + (size_t)r * 512;
  {
    int j0 = t, j1 = t + 256;
    float m0 = arow[((j0 + (p & 1)) & 7) * 3];
    float m1 = arow[((j1 + (p & 1)) & 7) * 3];
    float2 v0 = src[j0], v1 = src[j1];
    buf[0][j0] = make_float2(v0.x * m0, v0.y * m0);
    buf[0][j1] = make_float2(v1.x * m1, v1.y * m1);
  }
  FFT_CORE(512, 9, false)
  float2* row = U + (size_t)g * 512;
  row[t] = buf[cur][t];
  row[t + 256] = buf[cur][t + 256];
}

// --- 512 rows inverse, fused xH at load ---
__global__ __launch_bounds__(256) void k_r512_inv_H(
    float2* __restrict__ data, const float2* __restrict__ Hb) {
  __shared__ float2 buf[2][512];
  const int t = threadIdx.x;
  int g = blockIdx.x;
  float2* row = data + (size_t)g * 512;
  const float2* hrow = Hb + (size_t)(g & 511) * 512;
  {
    float2 a0 = row[t], h0 = hrow[t];
    float2 a1 = row[t + 256], h1 = hrow[t + 256];
    buf[0][t]       = make_float2(a0.x*h0.x - a0.y*h0.y, a0.x*h0.y + a0.y*h0.x);
    buf[0][t + 256] = make_float2(a1.x*h1.x - a1.y*h1.y, a1.x*h1.y + a1.y*h1.x);
  }
  FFT_CORE(512, 9, true)
  const float sc = 1.0f / 512.0f;
  float2 v0 = buf[cur][t], v1 = buf[cur][t + 256];
  row[t]       = make_float2(v0.x*sc, v0.y*sc);
  row[t + 256] = make_float2(v1.x*sc, v1.y*sc);
}

// --- 512 cols forward (CB=4 cols/block, W=64 workers) ---
__global__ __launch_bounds__(256) void k_c512_fwd(float2* __restrict__ data) {
  __shared__ float2 buf[2][512][4];
  const int c = threadIdx.x, w = threadIdx.y;
  float2* img = data + (size_t)blockIdx.y * RR2 + (size_t)blockIdx.x * 4 + c;
  for (int r = w; r < 512; r += 64) buf[0][r][c] = img[(size_t)r * 512];
  int m = 1, cur = 0;
  #pragma unroll
  for (int s = 0; s < 9; ++s) {
    __syncthreads();
    #pragma unroll
    for (int t = w; t < 256; t += 64) {
      int jm = t & ~(m - 1);
      float2 a = buf[cur][t][c];
      float2 b = buf[cur][t + 256][c];
      float ang = -6.2831853071795864769f * (float)jm * (1.0f / 512.0f);
      float sn, cs;
      __sincosf(ang, &sn, &cs);
      float2 d = make_float2(a.x - b.x, a.y - b.y);
      buf[cur ^ 1][t + jm][c]     = make_float2(a.x + b.x, a.y + b.y);
      buf[cur ^ 1][t + jm + m][c] = make_float2(d.x*cs - d.y*sn, d.x*sn + d.y*cs);
    }
    cur ^= 1; m <<= 1;
  }
  __syncthreads();
  for (int r = w; r < 512; r += 64) img[(size_t)r * 512] = buf[cur][r][c];
}

// --- 512 cols inverse, plain (for u1) ---
__global__ __launch_bounds__(256) void k_c512_inv(float2* __restrict__ data) {
  __shared__ float2 buf[2][512][4];
  const int c = threadIdx.x, w = threadIdx.y;
  float2* img = data + (size_t)blockIdx.y * RR2 + (size_t)blockIdx.x * 4 + c;
  for (int r = w; r < 512; r += 64) buf[0][r][c] = img[(size_t)r * 512];
  int m = 1, cur = 0;
  #pragma unroll
  for (int s = 0; s < 9; ++s) {
    __syncthreads();
    #pragma unroll
    for (int t = w; t < 256; t += 64) {
      int jm = t & ~(m - 1);
      float2 a = buf[cur][t][c];
      float2 b = buf[cur][t + 256][c];
      float ang = 6.2831853071795864769f * (float)jm * (1.0f / 512.0f);
      float sn, cs;
      __sincosf(ang, &sn, &cs);
      float2 d = make_float2(a.x - b.x, a.y - b.y);
      buf[cur ^ 1][t + jm][c]     = make_float2(a.x + b.x, a.y + b.y);
      buf[cur ^ 1][t + jm + m][c] = make_float2(d.x*cs - d.y*sn, d.x*sn + d.y*cs);
    }
    cur ^= 1; m <<= 1;
  }
  __syncthreads();
  const float sc = 1.0f / 512.0f;
  for (int r = w; r < 512; r += 64) {
    float2 v = buf[cur][r][c];
    img[(size_t)r * 512] = make_float2(v.x*sc, v.y*sc);
  }
}

// --- 512 cols inverse + |.|^2 + 2x2 downsample + PSF-sum (atomic) ---
__global__ __launch_bounds__(256) void k_c512_inv_psf(
    const float2* __restrict__ data, float* __restrict__ PSF, float* __restrict__ PSUM) {
  __shared__ float2 buf[2][512][4];
  __shared__ float red[256];
  const int c = threadIdx.x, w = threadIdx.y;
  const int p = blockIdx.y;
  const float2* img = data + (size_t)p * RR2 + (size_t)blockIdx.x * 4 + c;
  for (int r = w; r < 512; r += 64) buf[0][r][c] = img[(size_t)r * 512];
  int m = 1, cur = 0;
  #pragma unroll
  for (int s = 0; s < 9; ++s) {
    __syncthreads();
    #pragma unroll
    for (int t = w; t < 256; t += 64) {
      int jm = t & ~(m - 1);
      float2 a = buf[cur][t][c];
      float2 b = buf[cur][t + 256][c];
      float ang = 6.2831853071795864769f * (float)jm * (1.0f / 512.0f);
      float sn, cs;
      __sincosf(ang, &sn, &cs);
      float2 d = make_float2(a.x - b.x, a.y - b.y);
      buf[cur ^ 1][t + jm][c]     = make_float2(a.x + b.x, a.y + b.y);
      buf[cur ^ 1][t + jm + m][c] = make_float2(d.x*cs - d.y*sn, d.x*sn + d.y*cs);
    }
    cur ^= 1; m <<= 1;
  }
  __syncthreads();
  // scale for this pass is 1/512 (rows pass already applied its own);
  // psf = 0.25 * |v/512|^2 summed over 2x2
  const float sc2 = 0.25f / (512.0f * 512.0f);
  int t2 = w * 4 + c;              // 0..255 == output row
  float lsum = 0.f;
  #pragma unroll
  for (int oc = 0; oc < 2; ++oc) {
    float s = 0.f;
    #pragma unroll
    for (int dr = 0; dr < 2; ++dr)
      #pragma unroll
      for (int dc = 0; dc < 2; ++dc) {
        float2 v = buf[cur][2*t2 + dr][2*oc + dc];
        s += v.x*v.x + v.y*v.y;
      }
    float val = sc2 * s;
    PSF[(p << 16) | (t2 << 8) | (2*(int)blockIdx.x + oc)] = val;
    lsum += val;
  }
  red[t2] = lsum;
  __syncthreads();
  for (int o = 128; o > 0; o >>= 1) {
    if (t2 < o) red[t2] += red[t2 + o];
    __syncthreads();
  }
  if (t2 == 0) atomicAdd(PSUM + p, red[0]);
}

// --- 256 rows forward, fused OTF load (ifftshift + normalize) ---
__global__ __launch_bounds__(128) void k_r256_fwd_otf(
    const float* __restrict__ PSF, const float* __restrict__ PSUM,
    float2* __restrict__ OTF) {
  __shared__ float2 buf[2][256];
  const int t = threadIdx.x;
  int g = blockIdx.x;              // p*256 + i
  int p = g >> 8, i = g & 255;
  float inv = 1.0f / PSUM[p];
  int si = (i + 128) & 255;
  const float* prow = PSF + (p << 16) + (si << 8);
  buf[0][t]       = make_float2(prow[(t + 128) & 255] * inv, 0.f);
  buf[0][t + 128] = make_float2(prow[t] * inv, 0.f);
  FFT_CORE(256, 8, false)
  float2* row = OTF + (size_t)g * 256;
  row[t] = buf[cur][t];
  row[t + 128] = buf[cur][t + 128];
}

// --- 256 rows forward, fused input load (real, strided band) ---
__global__ __launch_bounds__(128) void k_r256_fwd_x(
    const float* __restrict__ in, float2* __restrict__ X, int band) {
  __shared__ float2 buf[2][256];
  const int t = threadIdx.x;
  int g = blockIdx.x;              // n*256 + i
  const float* src = in + (size_t)g * 256 * 3 + band;
  buf[0][t]       = make_float2(src[3*t], 0.f);
  buf[0][t + 128] = make_float2(src[3*(t+128)], 0.f);
  FFT_CORE(256, 8, false)
  float2* row = X + (size_t)g * 256;
  row[t] = buf[cur][t];
  row[t + 128] = buf[cur][t + 128];
}

// --- 256 rows inverse, fused 3-channel accumulate into out ---
__global__ __launch_bounds__(128) void k_r256_inv_accum(
    const float2* __restrict__ Y, float* __restrict__ out,
    const float* __restrict__ cf, int band) {
  __shared__ float2 buf[2][256];
  const int t = threadIdx.x;
  int g = blockIdx.x;              // n*256 + i
  const float2* row = Y + (size_t)g * 256;
  buf[0][t] = row[t];
  buf[0][t + 128] = row[t + 128];
  FFT_CORE(256, 8, true)
  const float sc = 1.0f / 256.0f;
  float c0 = cf[band], c1 = cf[3 + band], c2 = cf[9 + band];
  float* o = out + (size_t)g * 256 * 3;
  {
    float re = buf[cur][t].x * sc;
    o[3*t + 0] += c0 * re; o[3*t + 1] += c1 * re; o[3*t + 2] += c2 * re;
    float re2 = buf[cur][t + 128].x * sc;
    int j = t + 128;
    o[3*j + 0] += c0 * re2; o[3*j + 1] += c1 * re2; o[3*j + 2] += c2 * re2;
  }
}

// --- 256 cols forward (CB=8, W=32) ---
__global__ __launch_bounds__(256) void k_c256_fwd(float2* __restrict__ data) {
  __shared__ float2 buf[2][256][8];
  const int c = threadIdx.x, w = threadIdx.y;
  float2* img = data + (size_t)blockIdx.y * PP2 + (size_t)blockIdx.x * 8 + c;
  for (int r = w; r < 256; r += 32) buf[0][r][c] = img[(size_t)r * 256];
  int m = 1, cur = 0;
  #pragma unroll
  for (int s = 0; s < 8; ++s) {
    __syncthreads();
    #pragma unroll
    for (int t = w; t < 128; t += 32) {
      int jm = t & ~(m - 1);
      float2 a = buf[cur][t][c];
      float2 b = buf[cur][t + 128][c];
      float ang = -6.2831853071795864769f * (float)jm * (1.0f / 256.0f);
      float sn, cs;
      __sincosf(ang, &sn, &cs);
      float2 d = make_float2(a.x - b.x, a.y - b.y);
      buf[cur ^ 1][t + jm][c]     = make_float2(a.x + b.x, a.y + b.y);
      buf[cur ^ 1][t + jm + m][c] = make_float2(d.x*cs - d.y*sn, d.x*sn + d.y*cs);
    }
    cur ^= 1; m <<= 1;
  }
  __syncthreads();
  for (int r = w; r < 256; r += 32) img[(size_t)r * 256] = buf[cur][r][c];
}

// --- 256 cols inverse ---
__global__ __launch_bounds__(256) void k_c256_inv(float2* __restrict__ data) {
  __shared__ float2 buf[2][256][8];
  const int c = threadIdx.x, w = threadIdx.y;
  float2* img = data + (size_t)blockIdx.y * PP2 + (size_t)blockIdx.x * 8 + c;
  for (int r = w; r < 256; r += 32) buf[0][r][c] = img[(size_t)r * 256];
  int m = 1, cur = 0;
  #pragma unroll
  for (int s = 0; s < 8; ++s) {
    __syncthreads();
    #pragma unroll
    for (int t = w; t < 128; t += 32) {
      int jm = t & ~(m - 1);
      float2 a = buf[cur][t][c];
      float2 b = buf[cur][t + 128][c];
      float ang = 6.2831853071795864769f * (float)jm * (1.0f / 256.0f);
      float sn, cs;
      __sincosf(ang, &sn, &cs);
      float2 d = make_float2(a.x - b.x, a.y - b.y);
      buf[cur ^ 1][t + jm][c]     = make_float2(a.x + b.x, a.y + b.y);
      buf[cur ^ 1][t + jm + m][c] = make_float2(d.x*cs - d.y*sn, d.x*sn + d.y*cs);
    }
    cur ^= 1; m <<= 1;
  }
  __syncthreads();
  const float sc = 1.0f / 256.0f;
  for (int r = w; r < 256; r += 32) {
    float2 v = buf[cur][r][c];
    img[(size_t)r * 256] = make_float2(v.x*sc, v.y*sc);
  }
}

// --- W build: 9 nonzero taps from 4 distinct OTFs ---
// W_ab = (c_a*c_b/16) * S(a&1,b&1),  c0=2, c1=1-i, c3=1+i
__global__ void k_wbuild9(const float2* __restrict__ OTF, float2* __restrict__ Wb) {
  int uv = blockIdx.x * 256 + threadIdx.x;
  float2 O0 = OTF[uv];
  float2 O1 = OTF[(1 << 16) | uv];
  float2 O2 = OTF[(2 << 16) | uv];
  float2 O3 = OTF[(3 << 16) | uv];
  // S(p,q) = sum (-1)^(pG+qH) O[G*2+H]
  float2 S00 = make_float2(O0.x+O1.x+O2.x+O3.x, O0.y+O1.y+O2.y+O3.y);
  float2 S01 = make_float2(O0.x-O1.x+O2.x-O3.x, O0.y-O1.y+O2.y-O3.y);
  float2 S10 = make_float2(O0.x+O1.x-O2.x-O3.x, O0.y+O1.y-O2.y-O3.y);
  float2 S11 = make_float2(O0.x-O1.x-O2.x+O3.x, O0.y-O1.y-O2.y+O3.y);
  // constants k_m = c_a*c_b/16 for (a,b) in row-major {0,1,3}x{0,1,3}
  const float kr[9] = {0.25f, 0.125f, 0.125f, 0.125f, 0.f,     0.125f, 0.125f, 0.125f, 0.f};
  const float ki[9] = {0.f,  -0.125f, 0.125f,-0.125f,-0.125f,  0.f,    0.125f, 0.f,    0.125f};
  float2 S[4] = {S00, S01, S10, S11};
  #pragma unroll
  for (int m = 0; m < 9; ++m) {
    int pa = (m / 3 == 0) ? 0 : 1;     // parity of a in {0,1,3}
    int pb = (m % 3 == 0) ? 0 : 1;
    float2 s = S[pa*2 + pb];
    Wb[((size_t)m << 16) | uv] = make_float2(kr[m]*s.x - ki[m]*s.y,
                                             kr[m]*s.y + ki[m]*s.x);
  }
}

// --- Y_n = sum_{m=0..8} W_m .* shift_m(X_n) ---
__global__ void k_ybuild9(const float2* __restrict__ X, const float2* __restrict__ Wb,
                          float2* __restrict__ Y) {
  int idx = blockIdx.x * 256 + threadIdx.x;     // 8 * PP2
  int n = idx >> 16, uv = idx & 65535;
  int u = uv >> 8, v = uv & 255;
  const float2* Xn = X + ((size_t)n << 16);
  // du = (-64a)&255 for a in {0,1,3} -> {0,192,64}; same for dv
  const int dsh[3] = {0, 192, 64};
  float2 acc = make_float2(0.f, 0.f);
  #pragma unroll
  for (int ai = 0; ai < 3; ++ai) {
    int iu = (u + dsh[ai]) & 255;
    #pragma unroll
    for (int bi = 0; bi < 3; ++bi) {
      int iv = (v + dsh[bi]) & 255;
      float2 w = Wb[((size_t)(ai*3 + bi) << 16) | uv];
      float2 x = Xn[(iu << 8) | iv];
      acc.x += w.x*x.x - w.y*x.y;
      acc.y += w.x*x.y + w.y*x.x;
    }
  }
  Y[idx] = acc;
}

// ================= host-side dispatch =================

extern "C" void kernel_launch(void* const* d_in, const int* in_sizes, int n_in,
                              void* d_out, int out_size, void* d_ws, size_t ws_size,
                              hipStream_t stream) {
  const float* inp = (const float*)d_in[0];   // (8,256,256,3)
  const float* zc  = (const float*)d_in[1];   // (64,1,1)
  const float* zv  = (const float*)d_in[2];   // (64,512,512)
  const float* mp  = (const float*)d_in[3];   // (4,4,4)
  const float* cf  = (const float*)d_in[4];   // (4,3)
  float* out = (float*)d_out;                 // (8,256,256,3)

  char* ws = (char*)d_ws;
  size_t off = 0;
  auto alloc = [&](size_t bytes) -> void* {
    void* p = ws + off;
    off = (off + bytes + 255) & ~(size_t)255;
    return p;
  };
  float*  hm   = (float*) alloc((size_t)RR2 * 4);          // 1 MB
  float*  aux8 = (float*) alloc(192 * 4);
  float2* A    = (float2*)alloc((size_t)RR2 * 8);          // 2 MB (field/u1)
  float2* HB   = (float2*)alloc((size_t)RR2 * 8);          // 2 MB
  float2* U    = (float2*)alloc((size_t)4 * RR2 * 8);      // 8 MB (4 planes)
  float*  PSF  = (float*) alloc((size_t)4 * PP2 * 4);      // 1 MB
  float*  PSUM = (float*) alloc(4 * 4);
  float2* OTF  = (float2*)alloc((size_t)4 * PP2 * 8);      // 2 MB
  float2* Wb   = (float2*)alloc((size_t)9 * PP2 * 8);      // 4.5 MB
  float2* X    = (float2*)alloc((size_t)8 * PP2 * 8);      // 4 MB
  float2* Y    = (float2*)alloc((size_t)8 * PP2 * 8);      // 4 MB

  hipMemsetAsync(d_out, 0, (size_t)out_size * sizeof(float), stream);

  k_height<<<RR2 / 256, 256, 0, stream>>>(zc, zv, hm);
  k_aux<<<1, 192, 0, stream>>>(mp, cf, aux8);

  const double wls[3] = {4.6e-7, 5.4e-7, 6.2e-7};
  const double dn[3]  = {0.52, 0.515, 0.51};
  const double DIST = 0.05, DIST_CODE = 0.047;

  for (int b = 0; b < 3; ++b) {
    float K = (float)(2.0 * M_PI / wls[b] * dn[b]);
    // ---- u1 = IFFT( FFT(field) * H(dc) ) ----
    k_field<<<RR2 / 256, 256, 0, stream>>>(hm, A, K);
    k_transfer<<<RR2 / 256, 256, 0, stream>>>(HB, wls[b], DIST_CODE);
    k_r512_fwd<<<512, 256, 0, stream>>>(A);
    k_c512_fwd<<<dim3(128, 1), dim3(4, 64), 0, stream>>>(A);
    k_r512_inv_H<<<512, 256, 0, stream>>>(A, HB);
    k_c512_inv<<<dim3(128, 1), dim3(4, 64), 0, stream>>>(A);
    // ---- 4 distinct masked planes -> u3 -> PSF (fused) ----
    k_transfer<<<RR2 / 256, 256, 0, stream>>>(HB, wls[b], DIST - DIST_CODE);
    hipMemsetAsync(PSUM, 0, 4 * sizeof(float), stream);
    k_r512_fwd_expand<<<4 * 512, 256, 0, stream>>>(A, aux8, U, b);
    k_c512_fwd<<<dim3(128, 4), dim3(4, 64), 0, stream>>>(U);
    k_r512_inv_H<<<4 * 512, 256, 0, stream>>>(U, HB);
    k_c512_inv_psf<<<dim3(128, 4), dim3(4, 64), 0, stream>>>(U, PSF, PSUM);
    // ---- OTFs (4 planes) ----
    k_r256_fwd_otf<<<4 * 256, 128, 0, stream>>>(PSF, PSUM, OTF);
    k_c256_fwd<<<dim3(32, 4), dim3(8, 32), 0, stream>>>(OTF);
    k_wbuild9<<<PP2 / 256, 256, 0, stream>>>(OTF, Wb);
    // ---- convolution: 1 FFT + 9-tap combine + 1 IFFT per image ----
    k_r256_fwd_x<<<8 * 256, 128, 0, stream>>>(inp, X, b);
    k_c256_fwd<<<dim3(32, 8), dim3(8, 32), 0, stream>>>(X);
    k_ybuild9<<<8 * PP2 / 256, 256, 0, stream>>>(X, Wb, Y);
    k_c256_inv<<<dim3(32, 8), dim3(8, 32), 0, stream>>>(Y);
    k_r256_inv_accum<<<8 * 256, 128, 0, stream>>>(Y, out, cf, b);
  }
}

// Round 3
// 220.492 us; speedup vs baseline: 4.8127x; 1.8961x over previous
//
#include <hip/hip_runtime.h>
#include <math.h>

#define RR 512
#define RR2 (RR*RR)
#define PP 256
#define PP2 (PP*PP)

__constant__ double d_wls[3] = {4.6e-7, 5.4e-7, 6.2e-7};
__constant__ double d_dn[3]  = {0.52, 0.515, 0.51};

__device__ inline float2 cadd(float2 a, float2 b){ return make_float2(a.x+b.x, a.y+b.y); }
__device__ inline float2 csub(float2 a, float2 b){ return make_float2(a.x-b.x, a.y-b.y); }
__device__ inline float2 cmulf(float2 a, float2 b){ return make_float2(a.x*b.x-a.y*b.y, a.x*b.y+a.y*b.x); }

template<bool INV>
__device__ inline float2 cjrot(float2 z){ return INV ? make_float2(-z.y, z.x) : make_float2(z.y, -z.x); }

// One radix-4 DIF-Stockham butterfly. Element i lives at buf[i*STR + off].
// out[4j + r + q*m] = (sum_k a_k w4^{qk}) * W_N^{j*q},  j = (t/m)*m, r = t-j.
template<int N, int STR, bool INV>
__device__ inline void bfly4(const float2* __restrict__ in, float2* __restrict__ out,
                             int t, int m, int off) {
  int j = t & ~(m-1);
  float2 a0 = in[t*STR + off];
  float2 a1 = in[(t + N/4)*STR + off];
  float2 a2 = in[(t + N/2)*STR + off];
  float2 a3 = in[(t + 3*(N/4))*STR + off];
  float2 e0 = cadd(a0,a2), o0 = cadd(a1,a3);
  float2 e1 = csub(a0,a2), o1 = csub(a1,a3);
  float2 c0 = cadd(e0,o0), c2 = csub(e0,o0);
  float2 r1 = cjrot<INV>(o1);
  float2 c1 = cadd(e1,r1), c3 = csub(e1,r1);
  float ang = (INV ? 6.2831853071795865f : -6.2831853071795865f) * (float)j * (1.0f/(float)N);
  float sn, cs; __sincosf(ang, &sn, &cs);
  float2 w1 = make_float2(cs, sn);
  float2 w2 = make_float2(cs*cs - sn*sn, 2.f*cs*sn);
  float2 w3 = cmulf(w2, w1);
  int base = 4*j + (t - j);
  out[base*STR + off]       = c0;
  out[(base+m)*STR + off]   = cmulf(c1, w1);
  out[(base+2*m)*STR + off] = cmulf(c2, w2);
  out[(base+3*m)*STR + off] = cmulf(c3, w3);
}

// 512-pt rows: 128 threads, 4 radix-4 stages + twiddle-free radix-2. Result in b1.
template<bool INV>
__device__ inline void fft512_core(float2* __restrict__ b0, float2* __restrict__ b1, int t) {
  __syncthreads(); bfly4<512,1,INV>(b0,b1,t,1,0);
  __syncthreads(); bfly4<512,1,INV>(b1,b0,t,4,0);
  __syncthreads(); bfly4<512,1,INV>(b0,b1,t,16,0);
  __syncthreads(); bfly4<512,1,INV>(b1,b0,t,64,0);
  __syncthreads();
  #pragma unroll
  for (int k = 0; k < 2; ++k) {
    int tt = t + k*128;
    float2 a = b0[tt], b = b0[tt+256];
    b1[tt] = cadd(a,b); b1[tt+256] = csub(a,b);
  }
  __syncthreads();
}

// 256-pt rows: 64 threads (per row slice), 4 radix-4 stages. Result in b0.
template<bool INV>
__device__ inline void fft256_core(float2* __restrict__ b0, float2* __restrict__ b1, int t) {
  __syncthreads(); bfly4<256,1,INV>(b0,b1,t,1,0);
  __syncthreads(); bfly4<256,1,INV>(b1,b0,t,4,0);
  __syncthreads(); bfly4<256,1,INV>(b0,b1,t,16,0);
  __syncthreads(); bfly4<256,1,INV>(b1,b0,t,64,0);
  __syncthreads();
}

// 512-pt cols: CB=8 (pad 9), W=32 workers. Result in b1.
template<bool INV>
__device__ inline void fft512_core_col(float2* __restrict__ b0, float2* __restrict__ b1,
                                       int w, int c) {
  __syncthreads();
  #pragma unroll
  for (int k=0;k<4;++k) bfly4<512,9,INV>(b0,b1,w+32*k,1,c);
  __syncthreads();
  #pragma unroll
  for (int k=0;k<4;++k) bfly4<512,9,INV>(b1,b0,w+32*k,4,c);
  __syncthreads();
  #pragma unroll
  for (int k=0;k<4;++k) bfly4<512,9,INV>(b0,b1,w+32*k,16,c);
  __syncthreads();
  #pragma unroll
  for (int k=0;k<4;++k) bfly4<512,9,INV>(b1,b0,w+32*k,64,c);
  __syncthreads();
  #pragma unroll
  for (int k=0;k<8;++k) {
    int tt = w + 32*k;
    float2 a = b0[tt*9+c], b = b0[(tt+256)*9+c];
    b1[tt*9+c] = cadd(a,b); b1[(tt+256)*9+c] = csub(a,b);
  }
  __syncthreads();
}

// 256-pt cols: CB=8 (pad 9), W=32 workers. Result in b0.
template<bool INV>
__device__ inline void fft256_core_col(float2* __restrict__ b0, float2* __restrict__ b1,
                                       int w, int c) {
  __syncthreads();
  #pragma unroll
  for (int k=0;k<2;++k) bfly4<256,9,INV>(b0,b1,w+32*k,1,c);
  __syncthreads();
  #pragma unroll
  for (int k=0;k<2;++k) bfly4<256,9,INV>(b1,b0,w+32*k,4,c);
  __syncthreads();
  #pragma unroll
  for (int k=0;k<2;++k) bfly4<256,9,INV>(b0,b1,w+32*k,16,c);
  __syncthreads();
  #pragma unroll
  for (int k=0;k<2;++k) bfly4<256,9,INV>(b1,b0,w+32*k,64,c);
  __syncthreads();
}

// ---------------- height map (float4 vectorized) ----------------
__global__ void k_height4(const float* __restrict__ zc, const float4* __restrict__ zv,
                          float4* __restrict__ hm) {
  int idx = blockIdx.x * 256 + threadIdx.x;   // RR2/4
  float4 s = make_float4(0.f,0.f,0.f,0.f);
  #pragma unroll 8
  for (int t = 0; t < 64; ++t) {
    float c = zc[t];
    float4 v = zv[(size_t)t * (RR2/4) + idx];
    s.x += c*v.x; s.y += c*v.y; s.z += c*v.z; s.w += c*v.w;
  }
  hm[idx] = s;
}

// ---------------- aux 8x8x3 tile + PSUM zero ----------------
__global__ void k_aux(const float* __restrict__ mp, const float* __restrict__ cf,
                      float* __restrict__ aux8, float* __restrict__ PSUM) {
  int idx = threadIdx.x;           // 256 threads
  if (idx < 12) PSUM[idx] = 0.f;
  if (idx >= 192) return;
  int l = idx % 3, j = (idx / 3) & 7, i = idx / 24;
  int i4 = (i < 4) ? i : 7 - i;
  int j4 = (j < 4) ? j : 7 - j;
  float s = 0.f;
  for (int f = 0; f < 4; ++f) s += cf[f*3 + l] * mp[f*16 + i4*4 + j4];
  aux8[idx] = s;
}

// ---------------- transfer functions, 6 planes = 3 bands x {dc, d-dc} --------
__global__ void k_transfer(float2* __restrict__ HB) {
  int gid = blockIdx.x * 256 + threadIdx.x;   // 6 * RR2
  int p = gid >> 18, idx = gid & (RR2 - 1);
  int band = p >> 1;
  double wl = d_wls[band];
  double dist = (p & 1) ? (0.05 - 0.047) : 0.047;
  int u = idx >> 9, v = idx & 511;
  double inv_nd = 1.0 / (512.0 * 3.69e-6);
  double fu = (double)((u < 256) ? u : u - 512) * inv_nd;
  double fv = (double)((v < 256) ? v : v - 512) * inv_nd;
  double au = wl * fu, av = wl * fv;
  double argd = 1.0 - au*au - av*av;
  float2 h = make_float2(0.f, 0.f);
  if (argd > 0.0) {
    double kz = (6.283185307179586 / wl) * sqrt(argd);
    double ph = fmod(dist * kz, 6.283185307179586);
    float s, c;
    __sincosf((float)ph, &s, &c);
    h = make_float2(c, s);
  }
  HB[gid] = h;
}

// ---------------- fwd 512 rows fused with pupil-field build ----------------
__global__ __launch_bounds__(128) void k_r512f_field(
    const float* __restrict__ hm, float2* __restrict__ A) {
  __shared__ float2 b0[512], b1[512];
  int t = threadIdx.x;
  int g = blockIdx.x;            // band*512 + r
  int band = g >> 9, r = g & 511;
  float K = (float)(6.283185307179586 / d_wls[band] * d_dn[band]);
  const float* hrow = hm + (size_t)r * 512;
  int dx = r - 256;
  #pragma unroll
  for (int k = 0; k < 4; ++k) {
    int i = t + k*128;
    int dy = i - 256;
    float2 v = make_float2(0.f, 0.f);
    if (dx*dx + dy*dy < 65025) {
      float ph = K * hrow[i];
      float s, c;
      sincosf(ph, &s, &c);
      v = make_float2(c, s);
    }
    b0[i] = v;
  }
  fft512_core<false>(b0, b1, t);
  float2* row = A + (size_t)g * 512;
  #pragma unroll
  for (int k = 0; k < 4; ++k) { int i = t + k*128; row[i] = b1[i]; }
}

// ---------------- fwd 512 rows fused with mask expand ----------------
__global__ __launch_bounds__(128) void k_r512f_expand(
    const float2* __restrict__ A, const float* __restrict__ aux8,
    float2* __restrict__ U) {
  __shared__ float2 b0[512], b1[512];
  int t = threadIdx.x;
  int g = blockIdx.x;            // p*512 + r, p = band*4 + pm
  int p = g >> 9, r = g & 511;
  int band = p >> 2, pm = p & 3;
  int i8 = (r + (pm >> 1)) & 7;
  const float* arow = aux8 + i8*24 + band;
  const float2* src = A + ((size_t)band << 18) + (size_t)r * 512;
  #pragma unroll
  for (int k = 0; k < 4; ++k) {
    int i = t + k*128;
    float m = arow[((i + (pm & 1)) & 7) * 3];
    float2 v = src[i];
    b0[i] = make_float2(v.x*m, v.y*m);
  }
  fft512_core<false>(b0, b1, t);
  float2* row = U + (size_t)g * 512;
  #pragma unroll
  for (int k = 0; k < 4; ++k) { int i = t + k*128; row[i] = b1[i]; }
}

// ---------------- inv 512 rows fused with xH ----------------
__global__ __launch_bounds__(128) void k_r512_inv_H(
    float2* __restrict__ data, const float2* __restrict__ HB, int pshift, int hodd) {
  __shared__ float2 b0[512], b1[512];
  int t = threadIdx.x;
  int g = blockIdx.x;            // p*512 + r
  int p = g >> 9;
  int band = p >> pshift;
  const float2* hrow = HB + (((size_t)(band*2 + hodd)) << 18) + (size_t)(g & 511) * 512;
  float2* row = data + (size_t)g * 512;
  #pragma unroll
  for (int k = 0; k < 4; ++k) {
    int i = t + k*128;
    b0[i] = cmulf(row[i], hrow[i]);
  }
  fft512_core<true>(b0, b1, t);
  const float sc = 1.f/512.f;
  #pragma unroll
  for (int k = 0; k < 4; ++k) {
    int i = t + k*128;
    float2 v = b1[i];
    row[i] = make_float2(v.x*sc, v.y*sc);
  }
}

// ---------------- 512 cols fwd ----------------
__global__ __launch_bounds__(256) void k_c512_fwd(float2* __restrict__ data) {
  __shared__ float2 b0[512*9], b1[512*9];
  int c = threadIdx.x, w = threadIdx.y;          // (8,32)
  float2* img = data + ((size_t)blockIdx.y << 18) + (size_t)blockIdx.x * 8 + c;
  #pragma unroll
  for (int r = w; r < 512; r += 32) b0[r*9 + c] = img[(size_t)r * 512];
  fft512_core_col<false>(b0, b1, w, c);
  #pragma unroll
  for (int r = w; r < 512; r += 32) img[(size_t)r * 512] = b1[r*9 + c];
}

// ---------------- 512 cols inv (plain, scale) ----------------
__global__ __launch_bounds__(256) void k_c512_inv(float2* __restrict__ data) {
  __shared__ float2 b0[512*9], b1[512*9];
  int c = threadIdx.x, w = threadIdx.y;
  float2* img = data + ((size_t)blockIdx.y << 18) + (size_t)blockIdx.x * 8 + c;
  #pragma unroll
  for (int r = w; r < 512; r += 32) b0[r*9 + c] = img[(size_t)r * 512];
  fft512_core_col<true>(b0, b1, w, c);
  const float sc = 1.f/512.f;
  #pragma unroll
  for (int r = w; r < 512; r += 32) {
    float2 v = b1[r*9 + c];
    img[(size_t)r * 512] = make_float2(v.x*sc, v.y*sc);
  }
}

// ---------------- 512 cols inv + |.|^2 + 2x2 downsample + PSF sum ----------
__global__ __launch_bounds__(256) void k_c512_inv_psf(
    const float2* __restrict__ data, float* __restrict__ PSF, float* __restrict__ PSUM) {
  __shared__ float2 b0[512*9], b1[512*9];
  __shared__ float red[256];
  int c = threadIdx.x, w = threadIdx.y;
  int p = blockIdx.y;
  const float2* img = data + ((size_t)p << 18) + (size_t)blockIdx.x * 8 + c;
  #pragma unroll
  for (int r = w; r < 512; r += 32) b0[r*9 + c] = img[(size_t)r * 512];
  fft512_core_col<true>(b0, b1, w, c);
  const float sc2 = 0.25f / (512.f * 512.f);
  int tid = w * 8 + c;                 // 0..255 = output row
  float lsum = 0.f;
  #pragma unroll
  for (int oc = 0; oc < 4; ++oc) {
    float s = 0.f;
    #pragma unroll
    for (int dr = 0; dr < 2; ++dr)
      #pragma unroll
      for (int dc = 0; dc < 2; ++dc) {
        float2 v = b1[(2*tid + dr)*9 + (2*oc + dc)];
        s += v.x*v.x + v.y*v.y;
      }
    float val = sc2 * s;
    PSF[((size_t)p << 16) | (tid << 8) | (4*blockIdx.x + oc)] = val;
    lsum += val;
  }
  red[tid] = lsum;
  __syncthreads();
  for (int o = 128; o > 0; o >>= 1) { if (tid < o) red[tid] += red[tid+o]; __syncthreads(); }
  if (tid == 0) atomicAdd(PSUM + p, red[0]);
}

// ---------------- fwd 256 rows fused with OTF load (shift+normalize) --------
__global__ __launch_bounds__(128) void k_r256f_otf(
    const float* __restrict__ PSF, const float* __restrict__ PSUM,
    float2* __restrict__ OTF) {
  __shared__ float2 s0[2][256], s1[2][256];
  int t = threadIdx.x, ty = threadIdx.y;
  int g = blockIdx.x * 2 + ty;         // p*256 + i
  int p = g >> 8, i = g & 255;
  float inv = 1.0f / PSUM[p];
  int si = (i + 128) & 255;
  const float* prow = PSF + ((size_t)p << 16) + (si << 8);
  #pragma unroll
  for (int k = 0; k < 4; ++k) {
    int idx = t + k*64;
    s0[ty][idx] = make_float2(prow[(idx + 128) & 255] * inv, 0.f);
  }
  fft256_core<false>(s0[ty], s1[ty], t);
  float2* row = OTF + (size_t)g * 256;
  #pragma unroll
  for (int k = 0; k < 4; ++k) { int idx = t + k*64; row[idx] = s0[ty][idx]; }
}

// ---------------- fwd 256 rows fused with input load ----------------
__global__ __launch_bounds__(128) void k_r256f_x(
    const float* __restrict__ in, float2* __restrict__ X) {
  __shared__ float2 s0[2][256], s1[2][256];
  int t = threadIdx.x, ty = threadIdx.y;
  int g = blockIdx.x * 2 + ty;         // p*256 + i, p = band*8 + img
  int p = g >> 8, i = g & 255;
  int band = p >> 3, img = p & 7;
  const float* src = in + (((size_t)img * 256 + i) * 256) * 3 + band;
  #pragma unroll
  for (int k = 0; k < 4; ++k) {
    int idx = t + k*64;
    s0[ty][idx] = make_float2(src[idx*3], 0.f);
  }
  fft256_core<false>(s0[ty], s1[ty], t);
  float2* row = X + (size_t)g * 256;
  #pragma unroll
  for (int k = 0; k < 4; ++k) { int idx = t + k*64; row[idx] = s0[ty][idx]; }
}

// ---------------- 256 cols fwd / inv ----------------
__global__ __launch_bounds__(256) void k_c256_fwd(float2* __restrict__ data) {
  __shared__ float2 b0[256*9], b1[256*9];
  int c = threadIdx.x, w = threadIdx.y;          // (8,32)
  float2* img = data + ((size_t)blockIdx.y << 16) + (size_t)blockIdx.x * 8 + c;
  #pragma unroll
  for (int r = w; r < 256; r += 32) b0[r*9 + c] = img[(size_t)r * 256];
  fft256_core_col<false>(b0, b1, w, c);
  #pragma unroll
  for (int r = w; r < 256; r += 32) img[(size_t)r * 256] = b0[r*9 + c];
}

__global__ __launch_bounds__(256) void k_c256_inv(float2* __restrict__ data) {
  __shared__ float2 b0[256*9], b1[256*9];
  int c = threadIdx.x, w = threadIdx.y;
  float2* img = data + ((size_t)blockIdx.y << 16) + (size_t)blockIdx.x * 8 + c;
  #pragma unroll
  for (int r = w; r < 256; r += 32) b0[r*9 + c] = img[(size_t)r * 256];
  fft256_core_col<true>(b0, b1, w, c);
  const float sc = 1.f/256.f;
  #pragma unroll
  for (int r = w; r < 256; r += 32) {
    float2 v = b0[r*9 + c];
    img[(size_t)r * 256] = make_float2(v.x*sc, v.y*sc);
  }
}

// ---------------- S build: 4 parity combos of the 4 OTFs ----------------
__global__ void k_wbuild4(const float2* __restrict__ OTF, float2* __restrict__ Sb) {
  int gid = blockIdx.x * 256 + threadIdx.x;     // 3 * PP2
  int band = gid >> 16, uv = gid & 65535;
  const float2* O = OTF + ((size_t)(band*4) << 16);
  float2 O0 = O[uv];
  float2 O1 = O[(1<<16)|uv];
  float2 O2 = O[(2<<16)|uv];
  float2 O3 = O[(3<<16)|uv];
  float2* S = Sb + ((size_t)(band*4) << 16);
  S[uv]         = make_float2(O0.x+O1.x+O2.x+O3.x, O0.y+O1.y+O2.y+O3.y);
  S[(1<<16)|uv] = make_float2(O0.x-O1.x+O2.x-O3.x, O0.y-O1.y+O2.y-O3.y);
  S[(2<<16)|uv] = make_float2(O0.x+O1.x-O2.x-O3.x, O0.y+O1.y-O2.y-O3.y);
  S[(3<<16)|uv] = make_float2(O0.x-O1.x-O2.x+O3.x, O0.y-O1.y-O2.y+O3.y);
}

// ---------------- Y = sum_pq S_pq .* (class-combined X shifts) ----------------
__global__ void k_ybuild4(const float2* __restrict__ X, const float2* __restrict__ Sb,
                          float2* __restrict__ Y) {
  int idx = blockIdx.x * 256 + threadIdx.x;     // 24 * PP2
  int n = idx >> 16, uv = idx & 65535;
  int band = n >> 3;
  int u = uv >> 8, v = uv & 255;
  const float2* Xn = X + ((size_t)n << 16);
  const float2* S = Sb + ((size_t)(band*4) << 16);
  int ua = (u + 192) & 255, ub = (u + 64) & 255;
  int va = (v + 192) & 255, vb = (v + 64) & 255;
  int r0 = u << 8, r1 = ua << 8, r3 = ub << 8;
  float2 X00 = Xn[r0 | v];
  float2 X01 = Xn[r0 | va], X03 = Xn[r0 | vb];
  float2 X10 = Xn[r1 | v],  X30 = Xn[r3 | v];
  float2 X11 = Xn[r1 | va], X13 = Xn[r1 | vb];
  float2 X31 = Xn[r3 | va], X33 = Xn[r3 | vb];
  // k00*X00 ; (k01 X01 + k03 X03) = [X01+X03 + i(X03-X01)]/8 ; etc.
  float2 t00 = make_float2(0.25f*X00.x, 0.25f*X00.y);
  float2 t01 = make_float2(0.125f*(X01.x + X03.x - (X03.y - X01.y)),
                           0.125f*(X01.y + X03.y + (X03.x - X01.x)));
  float2 t10 = make_float2(0.125f*(X10.x + X30.x - (X30.y - X10.y)),
                           0.125f*(X10.y + X30.y + (X30.x - X10.x)));
  float2 t11 = make_float2(0.125f*(X13.x + X31.x - (X33.y - X11.y)),
                           0.125f*(X13.y + X31.y + (X33.x - X11.x)));
  float2 acc = cmulf(S[uv], t00);
  acc = cadd(acc, cmulf(S[(1<<16)|uv], t01));
  acc = cadd(acc, cmulf(S[(2<<16)|uv], t10));
  acc = cadd(acc, cmulf(S[(3<<16)|uv], t11));
  Y[idx] = acc;
}

// ---------------- inv 256 rows over 3 bands fused with color accumulate -----
__global__ __launch_bounds__(128) void k_r256_inv_accum3(
    const float2* __restrict__ Y, float* __restrict__ out,
    const float* __restrict__ cf) {
  __shared__ float2 s0[2][256], s1[2][256];
  int t = threadIdx.x, ty = threadIdx.y;
  int g = blockIdx.x * 2 + ty;         // img*256 + i
  int img = g >> 8, i = g & 255;
  float accR[4] = {0.f,0.f,0.f,0.f};
  float accG[4] = {0.f,0.f,0.f,0.f};
  float accB[4] = {0.f,0.f,0.f,0.f};
  for (int band = 0; band < 3; ++band) {
    const float2* row = Y + (((size_t)(band*8 + img)) << 16) + ((size_t)i << 8);
    #pragma unroll
    for (int k = 0; k < 4; ++k) s0[ty][t + k*64] = row[t + k*64];
    fft256_core<true>(s0[ty], s1[ty], t);
    float c0 = cf[band], c1 = cf[3 + band], c2 = cf[9 + band];
    const float sc = 1.f/256.f;
    #pragma unroll
    for (int k = 0; k < 4; ++k) {
      float re = s0[ty][t + k*64].x * sc;
      accR[k] += c0*re; accG[k] += c1*re; accB[k] += c2*re;
    }
  }
  #pragma unroll
  for (int k = 0; k < 4; ++k) {
    int col = t + k*64;
    float* o = out + (((size_t)img * 256 + i) * 256 + col) * 3;
    o[0] = accR[k]; o[1] = accG[k]; o[2] = accB[k];
  }
}

// ================= host-side dispatch =================

extern "C" void kernel_launch(void* const* d_in, const int* in_sizes, int n_in,
                              void* d_out, int out_size, void* d_ws, size_t ws_size,
                              hipStream_t stream) {
  const float* inp = (const float*)d_in[0];   // (8,256,256,3)
  const float* zc  = (const float*)d_in[1];   // (64,1,1)
  const float* zv  = (const float*)d_in[2];   // (64,512,512)
  const float* mp  = (const float*)d_in[3];   // (4,4,4)
  const float* cf  = (const float*)d_in[4];   // (4,3)
  float* out = (float*)d_out;                 // (8,256,256,3)

  char* ws = (char*)d_ws;
  size_t off = 0;
  auto alloc = [&](size_t bytes) -> void* {
    void* p = ws + off;
    off = (off + bytes + 255) & ~(size_t)255;
    return p;
  };
  float*  hm   = (float*) alloc((size_t)RR2 * 4);            // 1 MB
  float*  aux8 = (float*) alloc(256 * 4);
  float*  PSUM = (float*) alloc(64 * 4);
  float2* A    = (float2*)alloc((size_t)3 * RR2 * 8);        // 6 MB
  float2* HB   = (float2*)alloc((size_t)6 * RR2 * 8);        // 12 MB
  float2* U    = (float2*)alloc((size_t)12 * RR2 * 8);       // 24 MB
  float*  PSF  = (float*) alloc((size_t)12 * PP2 * 4);       // 3 MB
  float2* OTF  = (float2*)alloc((size_t)12 * PP2 * 8);       // 6 MB
  float2* Sb   = (float2*)alloc((size_t)12 * PP2 * 8);       // 6 MB
  float2* X    = U;                          // alias: U dead by conv stage
  float2* Y    = U + (size_t)24 * PP2;       // alias at +12 MB

  // ---- setup ----
  k_height4<<<RR2/4/256, 256, 0, stream>>>(zc, (const float4*)zv, (float4*)hm);
  k_aux<<<1, 256, 0, stream>>>(mp, cf, aux8, PSUM);
  k_transfer<<<6*RR2/256, 256, 0, stream>>>(HB);

  // ---- u1 for all 3 bands ----
  k_r512f_field<<<3*512, 128, 0, stream>>>(hm, A);
  k_c512_fwd<<<dim3(64, 3), dim3(8, 32), 0, stream>>>(A);
  k_r512_inv_H<<<3*512, 128, 0, stream>>>(A, HB, 0, 0);
  k_c512_inv<<<dim3(64, 3), dim3(8, 32), 0, stream>>>(A);

  // ---- 12 masked planes -> u3 -> PSFs (fused) ----
  k_r512f_expand<<<12*512, 128, 0, stream>>>(A, aux8, U);
  k_c512_fwd<<<dim3(64, 12), dim3(8, 32), 0, stream>>>(U);
  k_r512_inv_H<<<12*512, 128, 0, stream>>>(U, HB, 2, 1);
  k_c512_inv_psf<<<dim3(64, 12), dim3(8, 32), 0, stream>>>(U, PSF, PSUM);

  // ---- OTFs + parity combos ----
  k_r256f_otf<<<12*256/2, dim3(64, 2), 0, stream>>>(PSF, PSUM, OTF);
  k_c256_fwd<<<dim3(32, 12), dim3(8, 32), 0, stream>>>(OTF);
  k_wbuild4<<<3*PP2/256, 256, 0, stream>>>(OTF, Sb);

  // ---- convolution: FFT(X), 4-term combine, IFFT, accumulate ----
  k_r256f_x<<<24*256/2, dim3(64, 2), 0, stream>>>(inp, X);
  k_c256_fwd<<<dim3(32, 24), dim3(8, 32), 0, stream>>>(X);
  k_ybuild4<<<24*PP2/256, 256, 0, stream>>>(X, Sb, Y);
  k_c256_inv<<<dim3(32, 24), dim3(8, 32), 0, stream>>>(Y);
  k_r256_inv_accum3<<<8*256/2, dim3(64, 2), 0, stream>>>(Y, out, cf);
}